// Round 7
// baseline (257.969 us; speedup 1.0000x reference)
//
#include <hip/hip_runtime.h>
#include <math.h>

#define D_MODEL 512
#define N_HEADS 8
#define DK 64
#define QSCALE (0.0625f * 1.44269504089f)

typedef __attribute__((ext_vector_type(8))) short short8;
typedef __attribute__((ext_vector_type(4))) float f32x4;

typedef __attribute__((address_space(1))) const unsigned as1_uint;
typedef __attribute__((address_space(3))) unsigned as3_uint;

__device__ __forceinline__ unsigned short f2bf(float f) {
    unsigned u = __builtin_bit_cast(unsigned, f);
    u = (u + 0x7fff + ((u >> 16) & 1)) >> 16;   // RNE
    return (unsigned short)u;
}

// ---------------- x fp32 -> bf16 ----------------
__global__ __launch_bounds__(256) void cvt_x_kernel(const float* __restrict__ x,
                                                    unsigned short* __restrict__ xb, int n8)
{
    int i = blockIdx.x * 256 + threadIdx.x;
    if (i >= n8) return;
    float4 a = ((const float4*)x)[i * 2];
    float4 b = ((const float4*)x)[i * 2 + 1];
    short8 o;
    o[0] = f2bf(a.x); o[1] = f2bf(a.y); o[2] = f2bf(a.z); o[3] = f2bf(a.w);
    o[4] = f2bf(b.x); o[5] = f2bf(b.y); o[6] = f2bf(b.z); o[7] = f2bf(b.w);
    ((short8*)xb)[i] = o;
}

// ---------------- mask fp32 {0,0.5,1} -> u8 {0,1,2} ----------------
__global__ __launch_bounds__(256) void cvt_mask_kernel(const float* __restrict__ m,
                                                       unsigned char* __restrict__ mu, int n4)
{
    int i = blockIdx.x * 256 + threadIdx.x;
    if (i >= n4) return;
    float4 v = ((const float4*)m)[i];
    uchar4 o = { (unsigned char)(v.x * 2.0f + 0.5f),
                 (unsigned char)(v.y * 2.0f + 0.5f),
                 (unsigned char)(v.z * 2.0f + 0.5f),
                 (unsigned char)(v.w * 2.0f + 0.5f) };
    ((uchar4*)mu)[i] = o;
}

// ---------------- W [K][N] fp32 -> Wt [N][K] bf16 ----------------
__global__ __launch_bounds__(256) void cvt_wt_kernel(const float* __restrict__ W,
                                                     unsigned short* __restrict__ Wt)
{
    __shared__ float tile[64][65];
    int t = threadIdx.x;
    int c0 = blockIdx.x * 64;   // n
    int r0 = blockIdx.y * 64;   // k
    #pragma unroll
    for (int i = 0; i < 16; i++) {
        int e = i * 256 + t, r = e >> 6, c = e & 63;
        tile[c][r] = W[(size_t)(r0 + r) * D_MODEL + c0 + c];
    }
    __syncthreads();
    #pragma unroll
    for (int i = 0; i < 16; i++) {
        int e = i * 256 + t, n = e >> 6, kk = e & 63;
        Wt[(size_t)(c0 + n) * D_MODEL + r0 + kk] = f2bf(tile[n][kk]);
    }
}

// ---------------- fused QKV GEMM: [q|k|v] = x @ [Wq|Wk|Wv] + b ----------------
// Wt [1536][512] bf16 (rows: 0..511 q, 512..1023 k, 1024..1535 v)
// q: bf16 [bh][t][64] scaled by QSCALE; k: bf16 [bh][t][64]; v: bf16 [bh][64][T]
__global__ __launch_bounds__(512) void gemm_qkv_kernel(
    const unsigned short* __restrict__ A, const unsigned short* __restrict__ Wt,
    const float* __restrict__ bq, const float* __restrict__ bk, const float* __restrict__ bv,
    unsigned short* __restrict__ qb, unsigned short* __restrict__ kb,
    unsigned short* __restrict__ vb, int M, int T)
{
    constexpr int K = D_MODEL;
    __shared__ unsigned short As[2][128 * 32];
    __shared__ unsigned short Bs[2][128 * 32];
    int t = threadIdx.x;
    int lane = t & 63, w = t >> 6;
    int ql = lane & 15, kg = lane >> 4;
    int m0 = blockIdx.y * 128, n0 = blockIdx.x * 128;
    int wm = w >> 2, wn = w & 3;
    bool vmode = (n0 >= 1024);

    const unsigned short* srcA = A + (size_t)(m0 + (t >> 2)) * K + (t & 3) * 8;
    const unsigned short* srcB = Wt + (size_t)(n0 + (t >> 2)) * K + (t & 3) * 8;

    f32x4 acc[4][2];
    #pragma unroll
    for (int i = 0; i < 4; i++)
        #pragma unroll
        for (int j = 0; j < 2; j++) { f32x4 z = {0.f, 0.f, 0.f, 0.f}; acc[i][j] = z; }

    constexpr int NIT = K / 32;
    int cur = 0;
    __builtin_amdgcn_global_load_lds((as1_uint*)(srcA),
        (as3_uint*)((char*)&As[0][0] + w * 1024), 16, 0, 0);
    __builtin_amdgcn_global_load_lds((as1_uint*)(srcB),
        (as3_uint*)((char*)&Bs[0][0] + w * 1024), 16, 0, 0);
    __syncthreads();

    for (int it = 0; it < NIT; ++it) {
        if (it + 1 < NIT) {
            int k0 = (it + 1) * 32;
            __builtin_amdgcn_global_load_lds((as1_uint*)(srcA + k0),
                (as3_uint*)((char*)&As[cur ^ 1][0] + w * 1024), 16, 0, 0);
            __builtin_amdgcn_global_load_lds((as1_uint*)(srcB + k0),
                (as3_uint*)((char*)&Bs[cur ^ 1][0] + w * 1024), 16, 0, 0);
        }
        short8 af[4], bfr[2];
        #pragma unroll
        for (int fm = 0; fm < 4; fm++)
            af[fm] = *(const short8*)((const char*)&As[cur][0] + (wm * 64 + fm * 16 + ql) * 64 + kg * 16);
        #pragma unroll
        for (int fn = 0; fn < 2; fn++)
            bfr[fn] = *(const short8*)((const char*)&Bs[cur][0] + (wn * 32 + fn * 16 + ql) * 64 + kg * 16);
        if (vmode) {
            #pragma unroll
            for (int fm = 0; fm < 4; fm++)
                #pragma unroll
                for (int fn = 0; fn < 2; fn++)
                    acc[fm][fn] = __builtin_amdgcn_mfma_f32_16x16x32_bf16(bfr[fn], af[fm], acc[fm][fn], 0, 0, 0);
        } else {
            #pragma unroll
            for (int fm = 0; fm < 4; fm++)
                #pragma unroll
                for (int fn = 0; fn < 2; fn++)
                    acc[fm][fn] = __builtin_amdgcn_mfma_f32_16x16x32_bf16(af[fm], bfr[fn], acc[fm][fn], 0, 0, 0);
        }
        __syncthreads();
        cur ^= 1;
    }

    #pragma unroll
    for (int fm = 0; fm < 4; fm++) {
        #pragma unroll
        for (int fn = 0; fn < 2; fn++) {
            if (vmode) {
                int m = m0 + wm * 64 + fm * 16 + ql;
                int b = m / T, tt = m % T;
                #pragma unroll
                for (int r = 0; r < 4; r++) {
                    int n = (n0 - 1024) + wn * 32 + fn * 16 + kg * 4 + r;
                    float val = acc[fm][fn][r] + bv[n];
                    int h = n >> 6, d = n & 63;
                    vb[((size_t)(b * N_HEADS + h) * DK + d) * T + tt] = f2bf(val);
                }
            } else {
                int n = n0 + wn * 32 + fn * 16 + ql;
                int nn = n & 511;
                bool isq = (n0 < 512);
                float bn = isq ? bq[nn] : bk[nn];
                unsigned short* dst = isq ? qb : kb;
                int h = nn >> 6, d = nn & 63;
                #pragma unroll
                for (int r = 0; r < 4; r++) {
                    int m = m0 + wm * 64 + fm * 16 + kg * 4 + r;
                    int b = m / T, tt = m % T;
                    float val = acc[fm][fn][r] + bn;
                    if (isq) val *= QSCALE;
                    dst[((size_t)(b * N_HEADS + h) * T + tt) * DK + d] = f2bf(val);
                }
            }
        }
    }
}

// ---------------- out-proj GEMM: fp32 out = attb @ Wo + bo ----------------
__global__ __launch_bounds__(512) void gemm_out_kernel(
    const unsigned short* __restrict__ A, const unsigned short* __restrict__ Bt,
    const float* __restrict__ bias, float* __restrict__ outp, int M)
{
    constexpr int K = D_MODEL;
    __shared__ unsigned short As[2][128 * 32];
    __shared__ unsigned short Bs[2][128 * 32];
    int t = threadIdx.x;
    int lane = t & 63, w = t >> 6;
    int ql = lane & 15, kg = lane >> 4;
    int m0 = blockIdx.y * 128, n0 = blockIdx.x * 128;
    int wm = w >> 2, wn = w & 3;

    const unsigned short* srcA = A + (size_t)(m0 + (t >> 2)) * K + (t & 3) * 8;
    const unsigned short* srcB = Bt + (size_t)(n0 + (t >> 2)) * K + (t & 3) * 8;

    f32x4 acc[4][2];
    #pragma unroll
    for (int i = 0; i < 4; i++)
        #pragma unroll
        for (int j = 0; j < 2; j++) { f32x4 z = {0.f, 0.f, 0.f, 0.f}; acc[i][j] = z; }

    constexpr int NIT = K / 32;
    int cur = 0;
    __builtin_amdgcn_global_load_lds((as1_uint*)(srcA),
        (as3_uint*)((char*)&As[0][0] + w * 1024), 16, 0, 0);
    __builtin_amdgcn_global_load_lds((as1_uint*)(srcB),
        (as3_uint*)((char*)&Bs[0][0] + w * 1024), 16, 0, 0);
    __syncthreads();

    for (int it = 0; it < NIT; ++it) {
        if (it + 1 < NIT) {
            int k0 = (it + 1) * 32;
            __builtin_amdgcn_global_load_lds((as1_uint*)(srcA + k0),
                (as3_uint*)((char*)&As[cur ^ 1][0] + w * 1024), 16, 0, 0);
            __builtin_amdgcn_global_load_lds((as1_uint*)(srcB + k0),
                (as3_uint*)((char*)&Bs[cur ^ 1][0] + w * 1024), 16, 0, 0);
        }
        short8 af[4], bfr[2];
        #pragma unroll
        for (int fm = 0; fm < 4; fm++)
            af[fm] = *(const short8*)((const char*)&As[cur][0] + (wm * 64 + fm * 16 + ql) * 64 + kg * 16);
        #pragma unroll
        for (int fn = 0; fn < 2; fn++)
            bfr[fn] = *(const short8*)((const char*)&Bs[cur][0] + (wn * 32 + fn * 16 + ql) * 64 + kg * 16);
        #pragma unroll
        for (int fm = 0; fm < 4; fm++)
            #pragma unroll
            for (int fn = 0; fn < 2; fn++)
                acc[fm][fn] = __builtin_amdgcn_mfma_f32_16x16x32_bf16(af[fm], bfr[fn], acc[fm][fn], 0, 0, 0);
        __syncthreads();
        cur ^= 1;
    }

    #pragma unroll
    for (int fm = 0; fm < 4; fm++) {
        #pragma unroll
        for (int fn = 0; fn < 2; fn++) {
            int n = n0 + wn * 32 + fn * 16 + ql;
            float bn = bias[n];
            #pragma unroll
            for (int r = 0; r < 4; r++) {
                int m = m0 + wm * 64 + fm * 16 + kg * 4 + r;
                outp[(size_t)m * D_MODEL + n] = acc[fm][fn][r] + bn;
            }
        }
    }
}

// ---------------- MFMA flash attention v7: split-K x2, pipelined PV ----------------
// q pre-scaled by QSCALE; k [bh][T][64]; v [bh][64][T]; mu u8 [T][T].
// Partial outputs: opart [2][M][512] fp32, lpart [2][16][T] fp32 (additive).
__global__ __launch_bounds__(256) void attn_mfma_kernel(
    const unsigned short* __restrict__ q, const unsigned short* __restrict__ k,
    const unsigned short* __restrict__ v, const unsigned char* __restrict__ mu,
    float* __restrict__ opart, float* __restrict__ lpart, int B, int T)
{
    __shared__ unsigned short Ks[2][64 * 64];
    __shared__ unsigned short Vt[64 * 64];
    __shared__ unsigned short Ps[4][32 * 64];

    int t = threadIdx.x;
    int lane = t & 63, w = t >> 6;
    int ql = lane & 15, kg = lane >> 4;
    int bh = blockIdx.x, qt = blockIdx.y, z = blockIdx.z;
    int h = bh & (N_HEADS - 1), b = bh >> 3;
    int qr0 = qt * 128;
    int Th = T >> 1;
    int kv0 = z * Th;
    int nt = Th / 64;
    int M = B * T;

    const char* kbase = (const char*)(k + ((size_t)bh * T + kv0) * DK);
    const char* vbase = (const char*)(v + (size_t)bh * DK * T + kv0);

    // staging: LDS linear dest, inverse-swizzled global source
    int lin0 = w * 1024 + lane * 16;
    int lin1 = 4096 + lin0;
    int row0 = lin0 >> 7, row1 = lin1 >> 7;
    int sw0 = (row0 & 7) << 4, sw1 = (row1 & 7) << 4;
    const char* gK0 = kbase + (lin0 ^ sw0);
    const char* gK1 = kbase + (lin1 ^ sw1);
    const char* gV0 = vbase + (size_t)row0 * (2 * T) + ((lin0 & 127) ^ sw0);
    const char* gV1 = vbase + (size_t)row1 * (2 * T) + ((lin1 & 127) ^ sw1);

    short8 qfr[2][2];
    #pragma unroll
    for (int qf = 0; qf < 2; qf++) {
        const unsigned short* qrow = q + ((size_t)bh * T + qr0 + w * 32 + qf * 16 + ql) * DK + kg * 8;
        qfr[qf][0] = *(const short8*)(qrow);
        qfr[qf][1] = *(const short8*)(qrow + 32);
    }

    const unsigned char* mrow0 = mu + (size_t)(qr0 + w * 32 + ql) * T + kv0 + kg * 4;
    const unsigned char* mrow1 = mrow0 + (size_t)16 * T;

    f32x4 oacc[2][4];
    #pragma unroll
    for (int qf = 0; qf < 2; qf++)
        #pragma unroll
        for (int c = 0; c < 4; c++) { f32x4 zz = {0.f, 0.f, 0.f, 0.f}; oacc[qf][c] = zz; }
    float lacc0 = 0.f, lacc1 = 0.f;

    // prologue: mask(0) + K(0)->Ks[0]
    unsigned mcur0[4], mcur1[4];
    #pragma unroll
    for (int c = 0; c < 4; c++) {
        mcur0[c] = *(const unsigned*)(mrow0 + c * 16);
        mcur1[c] = *(const unsigned*)(mrow1 + c * 16);
    }
    __builtin_amdgcn_global_load_lds((as1_uint*)gK0, (as3_uint*)((char*)&Ks[0][0] + w * 1024), 16, 0, 0);
    __builtin_amdgcn_global_load_lds((as1_uint*)gK1, (as3_uint*)((char*)&Ks[0][0] + 4096 + w * 1024), 16, 0, 0);

    for (int kt = 0; kt < nt; kt++) {
        __syncthreads();   // Ks[cur]=K(kt) ready; Vt=V(kt-1) ready (kt>0)
        int cur = kt & 1;
        bool havenext = (kt + 1) < nt;

        unsigned mnxt0[4], mnxt1[4];
        if (havenext) {
            const unsigned char* mp0 = mrow0 + (size_t)(kt + 1) * 64;
            const unsigned char* mp1 = mrow1 + (size_t)(kt + 1) * 64;
            #pragma unroll
            for (int c = 0; c < 4; c++) {
                mnxt0[c] = *(const unsigned*)(mp0 + c * 16);
                mnxt1[c] = *(const unsigned*)(mp1 + c * 16);
            }
            size_t ko = (size_t)(kt + 1) * 8192;
            __builtin_amdgcn_global_load_lds((as1_uint*)(gK0 + ko),
                (as3_uint*)((char*)&Ks[cur ^ 1][0] + w * 1024), 16, 0, 0);
            __builtin_amdgcn_global_load_lds((as1_uint*)(gK1 + ko),
                (as3_uint*)((char*)&Ks[cur ^ 1][0] + 4096 + w * 1024), 16, 0, 0);
        }

        // PV(kt-1): reads Ps (written last iter) + Vt (V(kt-1))
        if (kt > 0) {
            __builtin_amdgcn_s_setprio(1);
            #pragma unroll
            for (int ks = 0; ks < 2; ks++) {
                int pboff = (ql * 128 + ks * 64 + kg * 16) ^ ((ql & 7) << 4);
                short8 pa0 = *(const short8*)((const char*)&Ps[w][0] + pboff);
                short8 pa1 = *(const short8*)((const char*)&Ps[w][0] + 2048 + pboff);
                #pragma unroll
                for (int c2 = 0; c2 < 4; c2++) {
                    int rowd = c2 * 16 + ql;
                    short8 vb = *(const short8*)((const char*)Vt +
                                ((rowd * 128 + ks * 64 + kg * 16) ^ ((rowd & 7) << 4)));
                    oacc[0][c2] = __builtin_amdgcn_mfma_f32_16x16x32_bf16(pa0, vb, oacc[0][c2], 0, 0, 0);
                    oacc[1][c2] = __builtin_amdgcn_mfma_f32_16x16x32_bf16(pa1, vb, oacc[1][c2], 0, 0, 0);
                }
            }
            __builtin_amdgcn_s_setprio(0);
        }

        // raw barrier: all waves done reading Vt (their ds_reads already consumed
        // by MFMA -> lgkm complete); no vmcnt drain so K-prefetch stays in flight
        __builtin_amdgcn_sched_barrier(0);
        __builtin_amdgcn_s_barrier();
        __builtin_amdgcn_sched_barrier(0);

        // stage V(kt) -> Vt; lands before next __syncthreads (hidden under QK+softmax)
        {
            size_t vo = (size_t)kt * 128;
            __builtin_amdgcn_global_load_lds((as1_uint*)(gV0 + vo),
                (as3_uint*)((char*)Vt + w * 1024), 16, 0, 0);
            __builtin_amdgcn_global_load_lds((as1_uint*)(gV1 + vo),
                (as3_uint*)((char*)Vt + 4096 + w * 1024), 16, 0, 0);
        }

        // QK^T (swapped): each kf read feeds both q-frags
        f32x4 sacc[2][4];
        #pragma unroll
        for (int qf = 0; qf < 2; qf++)
            #pragma unroll
            for (int c = 0; c < 4; c++) { f32x4 zz = {0.f, 0.f, 0.f, 0.f}; sacc[qf][c] = zz; }
        __builtin_amdgcn_s_setprio(1);
        #pragma unroll
        for (int ks = 0; ks < 2; ks++) {
            #pragma unroll
            for (int c = 0; c < 4; c++) {
                int row = c * 16 + ql;
                short8 kf = *(const short8*)((const char*)&Ks[cur][0] +
                            ((row * 128 + ks * 64 + kg * 16) ^ ((row & 7) << 4)));
                sacc[0][c] = __builtin_amdgcn_mfma_f32_16x16x32_bf16(kf, qfr[0][ks], sacc[0][c], 0, 0, 0);
                sacc[1][c] = __builtin_amdgcn_mfma_f32_16x16x32_bf16(kf, qfr[1][ks], sacc[1][c], 0, 0, 0);
            }
        }
        __builtin_amdgcn_s_setprio(0);

        // softmax: p = exp2(s * m), m in {0,1,2}; write P(kt) -> Ps
        #pragma unroll
        for (int c = 0; c < 4; c++) {
            unsigned mw = mcur0[c];
            float p0 = __builtin_amdgcn_exp2f(sacc[0][c][0] * (float)(mw & 0xffu));
            float p1 = __builtin_amdgcn_exp2f(sacc[0][c][1] * (float)((mw >> 8) & 0xffu));
            float p2 = __builtin_amdgcn_exp2f(sacc[0][c][2] * (float)((mw >> 16) & 0xffu));
            float p3 = __builtin_amdgcn_exp2f(sacc[0][c][3] * (float)(mw >> 24));
            lacc0 += (p0 + p1) + (p2 + p3);
            unsigned lo, hi;
            asm("v_cvt_pk_bf16_f32 %0, %1, %2" : "=v"(lo) : "v"(p0), "v"(p1));
            asm("v_cvt_pk_bf16_f32 %0, %1, %2" : "=v"(hi) : "v"(p2), "v"(p3));
            int byteoff = (ql * 128 + (c * 16 + kg * 4) * 2) ^ ((ql & 7) << 4);
            uint2 pr = { lo, hi };
            *(uint2*)((char*)&Ps[w][0] + byteoff) = pr;

            unsigned nw = mcur1[c];
            float q0 = __builtin_amdgcn_exp2f(sacc[1][c][0] * (float)(nw & 0xffu));
            float q1 = __builtin_amdgcn_exp2f(sacc[1][c][1] * (float)((nw >> 8) & 0xffu));
            float q2 = __builtin_amdgcn_exp2f(sacc[1][c][2] * (float)((nw >> 16) & 0xffu));
            float q3 = __builtin_amdgcn_exp2f(sacc[1][c][3] * (float)(nw >> 24));
            lacc1 += (q0 + q1) + (q2 + q3);
            unsigned lo1, hi1;
            asm("v_cvt_pk_bf16_f32 %0, %1, %2" : "=v"(lo1) : "v"(q0), "v"(q1));
            asm("v_cvt_pk_bf16_f32 %0, %1, %2" : "=v"(hi1) : "v"(q2), "v"(q3));
            uint2 pr1 = { lo1, hi1 };
            *(uint2*)((char*)&Ps[w][0] + 2048 + byteoff) = pr1;
        }

        if (havenext) {
            #pragma unroll
            for (int c = 0; c < 4; c++) { mcur0[c] = mnxt0[c]; mcur1[c] = mnxt1[c]; }
        }
    }

    __syncthreads();   // V(nt-1) DMA drained
    // final PV(nt-1)
    __builtin_amdgcn_s_setprio(1);
    #pragma unroll
    for (int ks = 0; ks < 2; ks++) {
        int pboff = (ql * 128 + ks * 64 + kg * 16) ^ ((ql & 7) << 4);
        short8 pa0 = *(const short8*)((const char*)&Ps[w][0] + pboff);
        short8 pa1 = *(const short8*)((const char*)&Ps[w][0] + 2048 + pboff);
        #pragma unroll
        for (int c2 = 0; c2 < 4; c2++) {
            int rowd = c2 * 16 + ql;
            short8 vb = *(const short8*)((const char*)Vt +
                        ((rowd * 128 + ks * 64 + kg * 16) ^ ((rowd & 7) << 4)));
            oacc[0][c2] = __builtin_amdgcn_mfma_f32_16x16x32_bf16(pa0, vb, oacc[0][c2], 0, 0, 0);
            oacc[1][c2] = __builtin_amdgcn_mfma_f32_16x16x32_bf16(pa1, vb, oacc[1][c2], 0, 0, 0);
        }
    }
    __builtin_amdgcn_s_setprio(0);

    // partial l and o writes (additive across z)
    lacc0 += __shfl_xor(lacc0, 16, 64);
    lacc0 += __shfl_xor(lacc0, 32, 64);
    lacc1 += __shfl_xor(lacc1, 16, 64);
    lacc1 += __shfl_xor(lacc1, 32, 64);
    if (kg == 0) {
        lpart[((size_t)z * 16 + bh) * T + qr0 + w * 32 + ql] = lacc0;
        lpart[((size_t)z * 16 + bh) * T + qr0 + w * 32 + 16 + ql] = lacc1;
    }
    #pragma unroll
    for (int qf = 0; qf < 2; qf++) {
        #pragma unroll
        for (int r = 0; r < 4; r++) {
            size_t rowo = ((size_t)z * M + (size_t)b * T + qr0 + w * 32 + qf * 16 + kg * 4 + r) * D_MODEL + h * DK;
            f32x4* oa = &oacc[qf][0];
            #pragma unroll
            for (int c2 = 0; c2 < 4; c2++)
                opart[rowo + c2 * 16 + ql] = oa[c2][r];
        }
    }
}

// ---------------- merge: attb = (o0+o1)/(l0+l1), bf16 ----------------
__global__ __launch_bounds__(256) void merge_kernel(
    const float* __restrict__ opart, const float* __restrict__ lpart,
    unsigned short* __restrict__ attb, int M, int T)
{
    int t = threadIdx.x;
    int lane = t & 63;
    int m = blockIdx.x * 4 + (t >> 6);
    int b = m / T, tt = m % T;
    int h = lane >> 3;
    size_t o0 = (size_t)m * D_MODEL + lane * 8;
    const float4* pa = (const float4*)(opart + o0);
    const float4* pb = (const float4*)(opart + (size_t)M * D_MODEL + o0);
    float4 a0 = pa[0], a1 = pa[1];
    float4 b0 = pb[0], b1 = pb[1];
    float l0 = lpart[(size_t)(b * N_HEADS + h) * T + tt];
    float l1 = lpart[(size_t)16 * T + (size_t)(b * N_HEADS + h) * T + tt];
    float r = 1.0f / (l0 + l1);
    short8 o;
    o[0] = f2bf((a0.x + b0.x) * r); o[1] = f2bf((a0.y + b0.y) * r);
    o[2] = f2bf((a0.z + b0.z) * r); o[3] = f2bf((a0.w + b0.w) * r);
    o[4] = f2bf((a1.x + b1.x) * r); o[5] = f2bf((a1.y + b1.y) * r);
    o[6] = f2bf((a1.z + b1.z) * r); o[7] = f2bf((a1.w + b1.w) * r);
    *(short8*)(attb + o0) = o;
}

extern "C" void kernel_launch(void* const* d_in, const int* in_sizes, int n_in,
                              void* d_out, int out_size, void* d_ws, size_t ws_size,
                              hipStream_t stream) {
    const float* x    = (const float*)d_in[0];
    const float* mask = (const float*)d_in[1];
    const float* Wq   = (const float*)d_in[2];
    const float* bq   = (const float*)d_in[3];
    const float* Wk   = (const float*)d_in[4];
    const float* bk   = (const float*)d_in[5];
    const float* Wv   = (const float*)d_in[6];
    const float* bv   = (const float*)d_in[7];
    const float* Wo   = (const float*)d_in[8];
    const float* bo   = (const float*)d_in[9];

    int T = (int)(sqrt((double)in_sizes[1]) + 0.5);   // 4096
    int C = D_MODEL;
    int B = in_sizes[0] / (T * C);                    // 2
    int M = B * T;

    size_t MK = (size_t)M * C;
    unsigned short* xb  = (unsigned short*)d_ws;
    unsigned short* Wtq = xb + MK;                    // [1536][512] contiguous
    unsigned short* Wtk = Wtq + (size_t)C * C;
    unsigned short* Wtv = Wtk + (size_t)C * C;
    unsigned short* Wto = Wtv + (size_t)C * C;
    unsigned short* qb  = Wto + (size_t)C * C;
    unsigned short* kb  = qb + MK;
    unsigned short* vb  = kb + MK;
    unsigned short* attb = vb + MK;
    unsigned char*  mu  = (unsigned char*)(attb + MK);
    float* opart = (float*)(mu + (size_t)T * T);
    float* lpart = opart + 2 * (size_t)M * C;

    int n8 = (int)(MK / 8);
    cvt_x_kernel<<<(n8 + 255) / 256, 256, 0, stream>>>(x, xb, n8);
    int n4 = T * T / 4;
    cvt_mask_kernel<<<(n4 + 255) / 256, 256, 0, stream>>>(mask, mu, n4);
    dim3 wtg(C / 64, C / 64, 1);
    cvt_wt_kernel<<<wtg, 256, 0, stream>>>(Wq, Wtq);
    cvt_wt_kernel<<<wtg, 256, 0, stream>>>(Wk, Wtk);
    cvt_wt_kernel<<<wtg, 256, 0, stream>>>(Wv, Wtv);
    cvt_wt_kernel<<<wtg, 256, 0, stream>>>(Wo, Wto);

    dim3 gq(3 * C / 128, M / 128, 1);
    gemm_qkv_kernel<<<gq, 512, 0, stream>>>(xb, Wtq, bq, bk, bv, qb, kb, vb, M, T);

    dim3 ga(B * N_HEADS, T / 128, 2);
    attn_mfma_kernel<<<ga, 256, 0, stream>>>(qb, kb, vb, mu, opart, lpart, B, T);

    merge_kernel<<<M / 4, 256, 0, stream>>>(opart, lpart, attb, M, T);

    dim3 gg(C / 128, M / 128, 1);
    gemm_out_kernel<<<gg, 512, 0, stream>>>(attb, Wto, bo, (float*)d_out, M);
}